// Round 18
// baseline (289.004 us; speedup 1.0000x reference)
//
#include <hip/hip_runtime.h>

#define N_NODES 100000
#define N_EDGES 1600000
#define N_GRAPHS 256
#define F_IN 38
#define F_PAD 40    // x packed to 40 f16 (80 B rows = 20 uints)
#define HID 64
#define CAPD 48     // dst-CSR capacity (in-deg Poisson(16); 48 proven)
#define KROW 52     // A'/W' LDS row stride in uints (96 f16 = 48 + 4 pad)

// edge partition parameters
#define NB   391    // dst buckets of 256 nodes: bucket = dst >> 8
#define EPB  4096   // edges per chunk-block
#define NBLK 391    // ceil(N_EDGES / EPB)
#define BCAP 4608   // per-bucket ebuf capacity (mean 4096, +8 sigma)

typedef unsigned short ushort;
typedef unsigned int uint;
typedef _Float16 h2 __attribute__((ext_vector_type(2)));
typedef _Float16 f16x8 __attribute__((ext_vector_type(8)));
typedef float f32x4 __attribute__((ext_vector_type(4)));

__device__ __forceinline__ h2 u2h(uint u) {
    union { uint u; h2 h; } v; v.u = u; return v.h;
}
__device__ __forceinline__ uint h2u(h2 h) {
    union { uint u; h2 h; } v; v.h = h; return v.u;
}
__device__ __forceinline__ ushort f2h_bits(float f) {
    union { _Float16 h; ushort s; } v; v.h = (_Float16)f; return v.s;
}
// Unwritten slots hold the harness poison 0xAAAAAAAA; unsigned-clamp them to
// the all-zero dummy row N_NODES (valid indices are < N_NODES, unchanged).
__device__ __forceinline__ int clampi(int v) {
    return (int)min((uint)v, (uint)N_NODES);
}

// ---------------------------------------------------------------------------
// Pack x [N][38] fp32 -> xb [N+1][40] f16 (zero cols 38..39; row N all-zero).
// Also zeroes the hb dummy row N.
// ---------------------------------------------------------------------------
__global__ void pack_x_kernel(const float* __restrict__ x,
                              ushort* __restrict__ xb,
                              ushort* __restrict__ hb) {
    int tid = blockIdx.x * blockDim.x + threadIdx.x;
    if (tid < HID) hb[(N_NODES << 6) + tid] = 0;
    if (tid >= (N_NODES + 1) * F_PAD) return;
    int n = tid / F_PAD;
    int f = tid - n * F_PAD;
    float v = (n < N_NODES && f < F_IN) ? x[n * F_IN + f] : 0.0f;
    xb[tid] = f2h_bits(v);
}

// ---------------------------------------------------------------------------
// Scatter edges into fixed-capacity bucket regions of ebuf (r13-proven).
// ---------------------------------------------------------------------------
__global__ void scatter_kernel(const int* __restrict__ src,
                               const int* __restrict__ dst,
                               int* __restrict__ gcur,
                               uint2* __restrict__ ebuf) {
    __shared__ int hist[NB];
    __shared__ int cur[NB];
    for (int i = threadIdx.x; i < NB; i += 256) hist[i] = 0;
    __syncthreads();
    const int base = blockIdx.x * EPB;
    int d[EPB / 256];
    #pragma unroll
    for (int i = 0; i < EPB / 256; ++i) {
        int e = base + i * 256 + threadIdx.x;
        d[i] = (e < N_EDGES) ? dst[e] : -1;
        if (d[i] >= 0) atomicAdd(&hist[d[i] >> 8], 1);
    }
    __syncthreads();
    for (int i = threadIdx.x; i < NB; i += 256) {
        int c = hist[i];
        cur[i] = (c > 0) ? atomicAdd(&gcur[i], c) : 0;
    }
    __syncthreads();
    #pragma unroll
    for (int i = 0; i < EPB / 256; ++i) {
        int e = base + i * 256 + threadIdx.x;
        if (d[i] >= 0) {
            int b = d[i] >> 8;
            int pos = atomicAdd(&cur[b], 1);
            if (pos < BCAP) ebuf[b * BCAP + pos] = make_uint2((uint)src[e], (uint)d[i]);
        }
    }
}

// ---------------------------------------------------------------------------
// One block per bucket builds its 256 nodes' slot lists (r13-proven).
// ---------------------------------------------------------------------------
__global__ void build_kernel(const uint2* __restrict__ ebuf,
                             const int* __restrict__ gcur,
                             int* __restrict__ cnt,
                             int* __restrict__ slots) {
    __shared__ int cl[256];
    const int b = blockIdx.x;
    cl[threadIdx.x] = 0;
    __syncthreads();
    int e1 = gcur[b]; if (e1 > BCAP) e1 = BCAP;
    for (int idx = threadIdx.x; idx < e1; idx += 256) {
        uint2 e = ebuf[b * BCAP + idx];
        int pos = atomicAdd(&cl[e.y & 255], 1);
        if (pos < CAPD) slots[(int)e.y * CAPD + pos] = (int)e.x;
    }
    __syncthreads();
    int n = (b << 8) + threadIdx.x;
    if (n < N_NODES) cnt[n] = cl[threadIdx.x];
}

// ---------------------------------------------------------------------------
// Layer 1 fused, MFMA Phase B. Per wave: D[16 nodes x 64 ch] = A'[16x96]W'[96x64]
// with A' = [agg40 | 0 | x40 | 0] f16 rows (stride KROW), W' = [w_rel;w_root]
// transposed [c][k] in LDS. 12 mfma_f32_16x16x32_f16 + 15 b128 reads replace
// r17's 800 LDS reads/wave (cycle model: 57 us of the 78 was LDS pipe).
// MFMA accs are AGPR-native -> no scratch-demotion risk (m97 precedent).
// Layouts (HW-verified per guide): A[m=lane&15][k=quad*8+j];
// B[k=quad*8+j][n=lane&15]; D row(m)=quad*4+reg, col(n)=lane&15.
// LDS 26.6 KB -> 6 blocks/CU. Keep launch_bounds(256,4) (5 forces spills r4/r7).
// ---------------------------------------------------------------------------
__global__ __launch_bounds__(256, 4) void layer1_kernel(
        const float* __restrict__ x,
        const uint* __restrict__ xb32,
        const int* __restrict__ cnt,
        const int* __restrict__ slots,
        const float* __restrict__ w_rel,
        const float* __restrict__ b_rel,
        const float* __restrict__ w_root,
        const int* __restrict__ batch,
        ushort* __restrict__ hb,
        float* __restrict__ hsum) {
    __shared__ __align__(16) uint s_w[64 * KROW];   // 13.3 KB  W'[c][k] f16 pairs
    __shared__ __align__(16) uint s_a[64 * KROW];   // 13.3 KB  A' rows (wave-private)

    // Stage W'[c][k]: k<38 -> w_rel[k][c]; 48<=k<86 -> w_root[k-48][c]; else 0.
    {
        const int c = threadIdx.x >> 2;          // 0..63
        const int k4 = threadIdx.x & 3;
        #pragma unroll
        for (int it = 0; it < 12; ++it) {
            int kk = k4 + 4 * it;                // pair index 0..47
            int k0 = 2 * kk, k1 = 2 * kk + 1;
            float v0 = 0.f, v1 = 0.f;
            if (k0 < F_IN)                 v0 = w_rel[k0 * HID + c];
            else if (k0 >= 48 && k0 < 86)  v0 = w_root[(k0 - 48) * HID + c];
            if (k1 < F_IN)                 v1 = w_rel[k1 * HID + c];
            else if (k1 >= 48 && k1 < 86)  v1 = w_root[(k1 - 48) * HID + c];
            s_w[c * KROW + kk] = (uint)f2h_bits(v0) | ((uint)f2h_bits(v1) << 16);
        }
    }
    const int wave = threadIdx.x >> 6, lane = threadIdx.x & 63;
    const int base = blockIdx.x * 64;

    // Phase A: gather (lanes 0-19, f16x2 pk_add, 16 rows in flight) + x row
    // (lanes 24-42 float2->f16x2) + zero pads. Wave-private s_a rows.
    for (int i = 0; i < 16; ++i) {
        int nl = wave * 16 + i;
        int n = base + nl;
        int dp = 0;
        if (n < N_NODES) {
            int deg = cnt[n]; if (deg > CAPD) deg = CAPD;
            dp = (deg + 15) & ~15; if (dp > CAPD) dp = CAPD;
        }
        h2 sum = {(_Float16)0, (_Float16)0};
        const int* sl = slots + n * CAPD;
        for (int j = 0; j < dp; j += 16) {
            int4 a4 = *(const int4*)(sl + j);
            int4 b4 = *(const int4*)(sl + j + 4);
            int4 c4 = *(const int4*)(sl + j + 8);
            int4 d4 = *(const int4*)(sl + j + 12);
            if (lane < 20) {
                uint v0 = xb32[clampi(a4.x) * 20 + lane];
                uint v1 = xb32[clampi(a4.y) * 20 + lane];
                uint v2 = xb32[clampi(a4.z) * 20 + lane];
                uint v3 = xb32[clampi(a4.w) * 20 + lane];
                uint v4 = xb32[clampi(b4.x) * 20 + lane];
                uint v5 = xb32[clampi(b4.y) * 20 + lane];
                uint v6 = xb32[clampi(b4.z) * 20 + lane];
                uint v7 = xb32[clampi(b4.w) * 20 + lane];
                uint v8 = xb32[clampi(c4.x) * 20 + lane];
                uint v9 = xb32[clampi(c4.y) * 20 + lane];
                uint va = xb32[clampi(c4.z) * 20 + lane];
                uint vb = xb32[clampi(c4.w) * 20 + lane];
                uint vc = xb32[clampi(d4.x) * 20 + lane];
                uint vd = xb32[clampi(d4.y) * 20 + lane];
                uint ve = xb32[clampi(d4.z) * 20 + lane];
                uint vf = xb32[clampi(d4.w) * 20 + lane];
                h2 t0 = (u2h(v0) + u2h(v1)) + (u2h(v2) + u2h(v3));
                h2 t1 = (u2h(v4) + u2h(v5)) + (u2h(v6) + u2h(v7));
                h2 t2 = (u2h(v8) + u2h(v9)) + (u2h(va) + u2h(vb));
                h2 t3 = (u2h(vc) + u2h(vd)) + (u2h(ve) + u2h(vf));
                sum += (t0 + t1) + (t2 + t3);
            }
        }
        uint* row = s_a + nl * KROW;
        if (lane < 20) {
            row[lane] = h2u(sum);                       // k pairs 0..19 (agg)
        } else if (lane < 24) {
            row[lane] = 0;                              // pairs 20..23 (pad)
        } else if (lane < 43) {
            uint xv = 0;
            int pidx = lane - 24;                       // 0..18
            if (n < N_NODES && pidx < 19) {
                float2 xf = *(const float2*)(x + n * F_IN + 2 * pidx);
                xv = (uint)f2h_bits(xf.x) | ((uint)f2h_bits(xf.y) << 16);
            }
            row[lane] = xv;                             // pairs 24..42 (x)
        } else if (lane < 48) {
            row[lane] = 0;                              // pairs 43..47 (pad)
        }
    }
    __syncthreads();   // weights (block-wide) + staging complete

    // Phase B: 4 N-tiles x 3 K-chunks of mfma_f32_16x16x32_f16
    const int quad = lane >> 4, l16 = lane & 15;
    const int mrow = wave * 16 + l16;
    f32x4 acc0 = {0.f, 0.f, 0.f, 0.f};
    f32x4 acc1 = acc0, acc2 = acc0, acc3 = acc0;
    union U4H8 { uint4 u; f16x8 h; };
    #pragma unroll
    for (int q = 0; q < 3; ++q) {
        const int ko = q * 16 + quad * 4;
        U4H8 a;  a.u  = *(const uint4*)&s_a[mrow * KROW + ko];
        U4H8 b0; b0.u = *(const uint4*)&s_w[(l16 + 0)  * KROW + ko];
        U4H8 b1; b1.u = *(const uint4*)&s_w[(l16 + 16) * KROW + ko];
        U4H8 b2; b2.u = *(const uint4*)&s_w[(l16 + 32) * KROW + ko];
        U4H8 b3; b3.u = *(const uint4*)&s_w[(l16 + 48) * KROW + ko];
        acc0 = __builtin_amdgcn_mfma_f32_16x16x32_f16(a.h, b0.h, acc0, 0, 0, 0);
        acc1 = __builtin_amdgcn_mfma_f32_16x16x32_f16(a.h, b1.h, acc1, 0, 0, 0);
        acc2 = __builtin_amdgcn_mfma_f32_16x16x32_f16(a.h, b2.h, acc2, 0, 0, 0);
        acc3 = __builtin_amdgcn_mfma_f32_16x16x32_f16(a.h, b3.h, acc3, 0, 0, 0);
    }

    // Epilogue: lane owns nodes m=quad*4+r (r=0..3) at channels l16+16t.
    const int c0 = l16, c1 = l16 + 16, c2 = l16 + 32, c3 = l16 + 48;
    const float bias0 = b_rel[c0], bias1 = b_rel[c1];
    const float bias2 = b_rel[c2], bias3 = b_rel[c3];
    float p0 = 0.f, p1 = 0.f, p2 = 0.f, p3 = 0.f;
    int cur_g = -1;
    #pragma unroll
    for (int r = 0; r < 4; ++r) {
        int n = base + wave * 16 + quad * 4 + r;
        if (n < N_NODES) {
            float h0 = fmaxf(acc0[r] + bias0, 0.f);
            float h1 = fmaxf(acc1[r] + bias1, 0.f);
            float h2v = fmaxf(acc2[r] + bias2, 0.f);
            float h3 = fmaxf(acc3[r] + bias3, 0.f);
            hb[(n << 6) + c0] = f2h_bits(h0);
            hb[(n << 6) + c1] = f2h_bits(h1);
            hb[(n << 6) + c2] = f2h_bits(h2v);
            hb[(n << 6) + c3] = f2h_bits(h3);
            int g = batch[n];
            if (g != cur_g) {
                if (cur_g >= 0) {
                    atomicAdd(&hsum[(cur_g << 6) + c0], p0);
                    atomicAdd(&hsum[(cur_g << 6) + c1], p1);
                    atomicAdd(&hsum[(cur_g << 6) + c2], p2);
                    atomicAdd(&hsum[(cur_g << 6) + c3], p3);
                }
                p0 = p1 = p2 = p3 = 0.f;
                cur_g = g;
            }
            p0 += h0; p1 += h1; p2 += h2v; p3 += h3;
        }
    }
    if (cur_g >= 0) {
        atomicAdd(&hsum[(cur_g << 6) + c0], p0);
        atomicAdd(&hsum[(cur_g << 6) + c1], p1);
        atomicAdd(&hsum[(cur_g << 6) + c2], p2);
        atomicAdd(&hsum[(cur_g << 6) + c3], p3);
    }
}

// ---------------------------------------------------------------------------
// Layer 2 (r17-proven): pure f16x2 gather + pool (lanes 0-31 = channel pairs).
// Per-graph Σ agg2 @ w2_rel = (Σ agg2) @ w2_rel -> GEMM lives in finalize.
// ---------------------------------------------------------------------------
__global__ __launch_bounds__(256, 4) void layer2_kernel(
        const uint* __restrict__ hb32,
        const int* __restrict__ cnt,
        const int* __restrict__ slots,
        const int* __restrict__ batch,
        float* __restrict__ esum) {
    const int wave = threadIdx.x >> 6, lane = threadIdx.x & 63;
    const int base = blockIdx.x * 64;

    float psum0 = 0.f, psum1 = 0.f;
    int cur_g = -1;
    for (int i = 0; i < 16; ++i) {
        int n = base + wave * 16 + i;
        if (n >= N_NODES) break;
        int deg = cnt[n]; if (deg > CAPD) deg = CAPD;
        int dp = (deg + 15) & ~15; if (dp > CAPD) dp = CAPD;
        h2 sum = {(_Float16)0, (_Float16)0};
        const int* sl = slots + n * CAPD;
        for (int j = 0; j < dp; j += 16) {
            int4 a4 = *(const int4*)(sl + j);
            int4 b4 = *(const int4*)(sl + j + 4);
            int4 c4 = *(const int4*)(sl + j + 8);
            int4 d4 = *(const int4*)(sl + j + 12);
            if (lane < 32) {
                uint v0 = hb32[(clampi(a4.x) << 5) + lane];
                uint v1 = hb32[(clampi(a4.y) << 5) + lane];
                uint v2 = hb32[(clampi(a4.z) << 5) + lane];
                uint v3 = hb32[(clampi(a4.w) << 5) + lane];
                uint v4 = hb32[(clampi(b4.x) << 5) + lane];
                uint v5 = hb32[(clampi(b4.y) << 5) + lane];
                uint v6 = hb32[(clampi(b4.z) << 5) + lane];
                uint v7 = hb32[(clampi(b4.w) << 5) + lane];
                uint v8 = hb32[(clampi(c4.x) << 5) + lane];
                uint v9 = hb32[(clampi(c4.y) << 5) + lane];
                uint va = hb32[(clampi(c4.z) << 5) + lane];
                uint vb = hb32[(clampi(c4.w) << 5) + lane];
                uint vc = hb32[(clampi(d4.x) << 5) + lane];
                uint vd = hb32[(clampi(d4.y) << 5) + lane];
                uint ve = hb32[(clampi(d4.z) << 5) + lane];
                uint vf = hb32[(clampi(d4.w) << 5) + lane];
                h2 t0 = (u2h(v0) + u2h(v1)) + (u2h(v2) + u2h(v3));
                h2 t1 = (u2h(v4) + u2h(v5)) + (u2h(v6) + u2h(v7));
                h2 t2 = (u2h(v8) + u2h(v9)) + (u2h(va) + u2h(vb));
                h2 t3 = (u2h(vc) + u2h(vd)) + (u2h(ve) + u2h(vf));
                sum += (t0 + t1) + (t2 + t3);
            }
        }
        if (lane < 32) {
            int g = batch[n];
            if (g != cur_g) {
                if (cur_g >= 0) {
                    atomicAdd(&esum[(cur_g << 6) + 2 * lane], psum0);
                    atomicAdd(&esum[(cur_g << 6) + 2 * lane + 1], psum1);
                }
                psum0 = 0.f; psum1 = 0.f;
                cur_g = g;
            }
            psum0 += (float)sum.x;
            psum1 += (float)sum.y;
        }
    }
    if (lane < 32 && cur_g >= 0) {
        atomicAdd(&esum[(cur_g << 6) + 2 * lane], psum0);
        atomicAdd(&esum[(cur_g << 6) + 2 * lane + 1], psum1);
    }
}

// ---------------------------------------------------------------------------
// out[g][c] = relu( (esum[g]@w2_rel + hsum[g]@w2_root + cnt*b2) / max(cnt,1) )
// ---------------------------------------------------------------------------
__global__ void finalize_kernel(const float* __restrict__ esum,
                                const float* __restrict__ hsum,
                                const float* __restrict__ w2_rel,
                                const float* __restrict__ w2_root,
                                const float* __restrict__ b2,
                                const int* __restrict__ batch,
                                float* __restrict__ out) {
    __shared__ float s_e[HID];
    __shared__ float s_h[HID];
    const int g = blockIdx.x;
    const int c = threadIdx.x;
    s_e[c] = esum[(g << 6) + c];
    s_h[c] = hsum[(g << 6) + c];
    __syncthreads();

    int lo = 0, hi = N_NODES;
    while (lo < hi) { int m = (lo + hi) >> 1; if (batch[m] < g) lo = m + 1; else hi = m; }
    int start = lo;
    hi = N_NODES;
    while (lo < hi) { int m = (lo + hi) >> 1; if (batch[m] < g + 1) lo = m + 1; else hi = m; }
    int cntg = lo - start;

    float acc = (float)cntg * b2[c];
    #pragma unroll
    for (int k = 0; k < HID; ++k) {
        acc += s_e[k] * w2_rel[k * HID + c];
        acc += s_h[k] * w2_root[k * HID + c];
    }
    float denom = cntg > 0 ? (float)cntg : 1.f;
    out[(g << 6) + c] = fmaxf(acc / denom, 0.f);
}

// ---------------------------------------------------------------------------
extern "C" void kernel_launch(void* const* d_in, const int* in_sizes, int n_in,
                              void* d_out, int out_size, void* d_ws, size_t ws_size,
                              hipStream_t stream) {
    const float* x       = (const float*)d_in[0];
    const int*   ei      = (const int*)  d_in[1];
    const int*   batch   = (const int*)  d_in[2];
    const float* w1_rel  = (const float*)d_in[3];
    const float* b1_rel  = (const float*)d_in[4];
    const float* w1_root = (const float*)d_in[5];
    const float* w2_rel  = (const float*)d_in[6];
    const float* b2_rel  = (const float*)d_in[7];
    const float* w2_root = (const float*)d_in[8];
    float* out = (float*)d_out;

    const int* src = ei;
    const int* dst = ei + N_EDGES;

    // ws layout (bytes), peak ~40.5 MB (same as r16/r17):
    //   [0,       400000)   cnt    N int   (written by build_kernel)
    //   [400000,  465536)   hsum   256*64 f32 (zeroed)
    //   [465536,  531072)   esum   256*64 f32 (zeroed)
    //   [531072,  532636)   gcur   NB int  (zeroed)
    //   [532640, 19732640)  slots  N*48 int (unwritten tail = poison, clamped)
    //   [19732640,27732720) xb     (N+1)*40 f16  } ebuf (391*4608 uint2)
    //   [27732720,40532848) hb     (N+1)*64 f16  } aliases xb+hb; dead
    //   [19732640,34147488) ebuf (alias)           before pack_x runs
    char* wsb = (char*)d_ws;
    int*    cnt   = (int*)   (wsb);
    float*  hsum  = (float*) (wsb + 400000);
    float*  esum  = (float*) (wsb + 465536);
    int*    gcur  = (int*)   (wsb + 531072);
    int*    slots = (int*)   (wsb + 532640);
    ushort* xb    = (ushort*)(wsb + 19732640);
    ushort* hb    = (ushort*)(wsb + 27732720);
    uint2*  ebuf  = (uint2*) (wsb + 19732640);   // alias, see above

    hipMemsetAsync(wsb + 400000, 0, 132636, stream);  // hsum + esum + gcur

    scatter_kernel<<<NBLK, 256, 0, stream>>>(src, dst, gcur, ebuf);
    build_kernel<<<NB, 256, 0, stream>>>(ebuf, gcur, cnt, slots);

    {   // pack x -> f16 [N+1][40]; zero hb dummy row (after ebuf is dead)
        int total = (N_NODES + 1) * F_PAD;
        pack_x_kernel<<<(total + 255) / 256, 256, 0, stream>>>(x, xb, hb);
    }
    {   // layer 1 (gather + MFMA dense + relu + hsum pooling)
        int blocks = (N_NODES + 63) / 64;
        layer1_kernel<<<blocks, 256, 0, stream>>>(x, (const uint*)xb, cnt, slots,
                                                  w1_rel, b1_rel, w1_root, batch,
                                                  hb, hsum);
    }
    {   // layer 2: gather + per-graph pooling only
        int blocks = (N_NODES + 63) / 64;
        layer2_kernel<<<blocks, 256, 0, stream>>>((const uint*)hb, cnt, slots,
                                                  batch, esum);
    }
    {   // finalize: esum@w2_rel + hsum@w2_root + bias, mean, relu
        finalize_kernel<<<N_GRAPHS, HID, 0, stream>>>(esum, hsum, w2_rel, w2_root,
                                                      b2_rel, batch, out);
    }
}

// Round 19
// 256.169 us; speedup vs baseline: 1.1282x; 1.1282x over previous
//
#include <hip/hip_runtime.h>

#define N_NODES 100000
#define N_EDGES 1600000
#define N_GRAPHS 256
#define F_IN 38
#define F_PAD 40    // x packed to 40 f16 (80 B rows = 20 uints)
#define HID 64
#define CAPD 48     // dst-CSR capacity (in-deg Poisson(16); 48 proven)

// edge partition parameters
#define NB   391    // dst buckets of 256 nodes: bucket = dst >> 8
#define EPB  4096   // edges per chunk-block
#define NBLK 391    // ceil(N_EDGES / EPB)
#define BCAP 4608   // per-bucket ebuf capacity (mean 4096, +8 sigma)

typedef unsigned short ushort;
typedef unsigned int uint;
typedef _Float16 h2 __attribute__((ext_vector_type(2)));

__device__ __forceinline__ h2 u2h(uint u) {
    union { uint u; h2 h; } v; v.u = u; return v.h;
}
__device__ __forceinline__ uint h2u(h2 h) {
    union { uint u; h2 h; } v; v.h = h; return v.u;
}
__device__ __forceinline__ ushort f2h_bits(float f) {
    union { _Float16 h; ushort s; } v; v.h = (_Float16)f; return v.s;
}
// Unwritten slots hold the harness poison 0xAAAAAAAA; unsigned-clamp them to
// the all-zero dummy row N_NODES (valid indices are < N_NODES, unchanged).
__device__ __forceinline__ int clampi(int v) {
    return (int)min((uint)v, (uint)N_NODES);
}

// ---------------------------------------------------------------------------
// Pack x [N][38] fp32 -> xb [N+1][40] f16 (zero cols 38..39; row N all-zero).
// Also zeroes the hb dummy row N.
// ---------------------------------------------------------------------------
__global__ void pack_x_kernel(const float* __restrict__ x,
                              ushort* __restrict__ xb,
                              ushort* __restrict__ hb) {
    int tid = blockIdx.x * blockDim.x + threadIdx.x;
    if (tid < HID) hb[(N_NODES << 6) + tid] = 0;
    if (tid >= (N_NODES + 1) * F_PAD) return;
    int n = tid / F_PAD;
    int f = tid - n * F_PAD;
    float v = (n < N_NODES && f < F_IN) ? x[n * F_IN + f] : 0.0f;
    xb[tid] = f2h_bits(v);
}

// ---------------------------------------------------------------------------
// Scatter edges into fixed-capacity bucket regions of ebuf (r13-proven).
// ---------------------------------------------------------------------------
__global__ void scatter_kernel(const int* __restrict__ src,
                               const int* __restrict__ dst,
                               int* __restrict__ gcur,
                               uint2* __restrict__ ebuf) {
    __shared__ int hist[NB];
    __shared__ int cur[NB];
    for (int i = threadIdx.x; i < NB; i += 256) hist[i] = 0;
    __syncthreads();
    const int base = blockIdx.x * EPB;
    int d[EPB / 256];
    #pragma unroll
    for (int i = 0; i < EPB / 256; ++i) {
        int e = base + i * 256 + threadIdx.x;
        d[i] = (e < N_EDGES) ? dst[e] : -1;
        if (d[i] >= 0) atomicAdd(&hist[d[i] >> 8], 1);
    }
    __syncthreads();
    for (int i = threadIdx.x; i < NB; i += 256) {
        int c = hist[i];
        cur[i] = (c > 0) ? atomicAdd(&gcur[i], c) : 0;
    }
    __syncthreads();
    #pragma unroll
    for (int i = 0; i < EPB / 256; ++i) {
        int e = base + i * 256 + threadIdx.x;
        if (d[i] >= 0) {
            int b = d[i] >> 8;
            int pos = atomicAdd(&cur[b], 1);
            if (pos < BCAP) ebuf[b * BCAP + pos] = make_uint2((uint)src[e], (uint)d[i]);
        }
    }
}

// ---------------------------------------------------------------------------
// One block per bucket builds its 256 nodes' slot lists (r13-proven).
// ---------------------------------------------------------------------------
__global__ void build_kernel(const uint2* __restrict__ ebuf,
                             const int* __restrict__ gcur,
                             int* __restrict__ cnt,
                             int* __restrict__ slots) {
    __shared__ int cl[256];
    const int b = blockIdx.x;
    cl[threadIdx.x] = 0;
    __syncthreads();
    int e1 = gcur[b]; if (e1 > BCAP) e1 = BCAP;
    for (int idx = threadIdx.x; idx < e1; idx += 256) {
        uint2 e = ebuf[b * BCAP + idx];
        int pos = atomicAdd(&cl[e.y & 255], 1);
        if (pos < CAPD) slots[(int)e.y * CAPD + pos] = (int)e.x;
    }
    __syncthreads();
    int n = (b << 8) + threadIdx.x;
    if (n < N_NODES) cnt[n] = cl[threadIdx.x];
}

// ---------------------------------------------------------------------------
// Layer 1 fused (r17 Phase B, dual-node Phase A): lanes 0-31 gather the even
// node, lanes 32-63 the odd node (l32<20 active per half) -> 32 rows in
// flight per wave (2x MLP vs r17). Phase B = v_pk_fma vs pair-packed LDS
// weights, SINGLE h2 accumulator (r11/r12/r14: widened per-thread Phase-B
// state gets scratch-demoted, WRITE 0.5-1.9 GB). r18's MFMA variant lost to
// bank conflicts + occupancy; reverted. NOTE: rounds 4/7 FETCH-blowup was
// the (256,5) spill, NOT half-wave loads (r7 full-wave reproduced it).
// LDS 20 KB. Keep launch_bounds(256,4).
// ---------------------------------------------------------------------------
__global__ __launch_bounds__(256, 4) void layer1_kernel(
        const uint* __restrict__ xb32,
        const int* __restrict__ cnt,
        const int* __restrict__ slots,
        const float* __restrict__ w_rel,
        const float* __restrict__ b_rel,
        const float* __restrict__ w_root,
        const int* __restrict__ batch,
        ushort* __restrict__ hb,
        float* __restrict__ hsum) {
    __shared__ uint s_wrelp[20 * HID];   // 5 KB: (w[2k][c], w[2k+1][c]) f16x2
    __shared__ uint s_wrootp[20 * HID];  // 5 KB
    __shared__ uint s_a[64][20];         // 5 KB gathered sums (f16x2)
    __shared__ uint s_x[64][20];         // 5 KB own rows (f16x2)
    for (int i = threadIdx.x; i < 20 * HID; i += 256) {
        int kk = i >> 6, cc = i & 63;
        int k0 = 2 * kk, k1 = 2 * kk + 1;
        float r0 = (k0 < F_IN) ? w_rel[k0 * HID + cc] : 0.f;
        float r1 = (k1 < F_IN) ? w_rel[k1 * HID + cc] : 0.f;
        float o0 = (k0 < F_IN) ? w_root[k0 * HID + cc] : 0.f;
        float o1 = (k1 < F_IN) ? w_root[k1 * HID + cc] : 0.f;
        s_wrelp[i]  = (uint)f2h_bits(r0) | ((uint)f2h_bits(r1) << 16);
        s_wrootp[i] = (uint)f2h_bits(o0) | ((uint)f2h_bits(o1) << 16);
    }
    const int wave = threadIdx.x >> 6, lane = threadIdx.x & 63;
    const int half = lane >> 5, l32 = lane & 31;
    const int base = blockIdx.x * 64;

    // Phase A: 2 nodes per iteration, 32 row-loads in flight per wave
    for (int i = 0; i < 8; ++i) {
        int nl = wave * 16 + 2 * i + half;
        int n = base + nl;
        uint xv = 0;
        int dp = 0;
        if (n < N_NODES) {
            int deg = cnt[n]; if (deg > CAPD) deg = CAPD;
            dp = (deg + 15) & ~15; if (dp > CAPD) dp = CAPD;
            if (l32 < 20) xv = xb32[n * 20 + l32];
        }
        h2 sum = {(_Float16)0, (_Float16)0};
        const int* sl = slots + n * CAPD;
        for (int j = 0; j < dp; j += 16) {
            int4 a4 = *(const int4*)(sl + j);
            int4 b4 = *(const int4*)(sl + j + 4);
            int4 c4 = *(const int4*)(sl + j + 8);
            int4 d4 = *(const int4*)(sl + j + 12);
            if (l32 < 20) {
                uint v0 = xb32[clampi(a4.x) * 20 + l32];
                uint v1 = xb32[clampi(a4.y) * 20 + l32];
                uint v2 = xb32[clampi(a4.z) * 20 + l32];
                uint v3 = xb32[clampi(a4.w) * 20 + l32];
                uint v4 = xb32[clampi(b4.x) * 20 + l32];
                uint v5 = xb32[clampi(b4.y) * 20 + l32];
                uint v6 = xb32[clampi(b4.z) * 20 + l32];
                uint v7 = xb32[clampi(b4.w) * 20 + l32];
                uint v8 = xb32[clampi(c4.x) * 20 + l32];
                uint v9 = xb32[clampi(c4.y) * 20 + l32];
                uint va = xb32[clampi(c4.z) * 20 + l32];
                uint vb = xb32[clampi(c4.w) * 20 + l32];
                uint vc = xb32[clampi(d4.x) * 20 + l32];
                uint vd = xb32[clampi(d4.y) * 20 + l32];
                uint ve = xb32[clampi(d4.z) * 20 + l32];
                uint vf = xb32[clampi(d4.w) * 20 + l32];
                h2 t0 = (u2h(v0) + u2h(v1)) + (u2h(v2) + u2h(v3));
                h2 t1 = (u2h(v4) + u2h(v5)) + (u2h(v6) + u2h(v7));
                h2 t2 = (u2h(v8) + u2h(v9)) + (u2h(va) + u2h(vb));
                h2 t3 = (u2h(vc) + u2h(vd)) + (u2h(ve) + u2h(vf));
                sum += (t0 + t1) + (t2 + t3);
            }
        }
        if (l32 < 20) {
            s_a[nl][l32] = h2u(sum);
            s_x[nl][l32] = xv;
        }
    }
    __syncthreads();

    // Phase B: pk_fma against pair-packed weights; single h2 accumulator
    const int c = lane, r = wave;
    const float bias = b_rel[c];
    float psum = 0.f;
    int cur_g = -1;
    for (int i = 0; i < 16; ++i) {
        int nl = r * 16 + i;
        int n = base + nl;
        if (n >= N_NODES) break;
        h2 acc = {(_Float16)0, (_Float16)0};
        #pragma unroll
        for (int k8 = 0; k8 < 5; ++k8) {   // 4 pairs = 8 features per iter
            uint4 pa = *(const uint4*)&s_a[nl][k8 * 4];
            uint4 px = *(const uint4*)&s_x[nl][k8 * 4];
            acc += u2h(pa.x) * u2h(s_wrelp[(k8 * 4 + 0) * HID + c]);
            acc += u2h(pa.y) * u2h(s_wrelp[(k8 * 4 + 1) * HID + c]);
            acc += u2h(pa.z) * u2h(s_wrelp[(k8 * 4 + 2) * HID + c]);
            acc += u2h(pa.w) * u2h(s_wrelp[(k8 * 4 + 3) * HID + c]);
            acc += u2h(px.x) * u2h(s_wrootp[(k8 * 4 + 0) * HID + c]);
            acc += u2h(px.y) * u2h(s_wrootp[(k8 * 4 + 1) * HID + c]);
            acc += u2h(px.z) * u2h(s_wrootp[(k8 * 4 + 2) * HID + c]);
            acc += u2h(px.w) * u2h(s_wrootp[(k8 * 4 + 3) * HID + c]);
        }
        float hv = fmaxf((float)acc.x + (float)acc.y + bias, 0.f);
        hb[(n << 6) + c] = f2h_bits(hv);
        int g = batch[n];
        if (g != cur_g) {
            if (cur_g >= 0) atomicAdd(&hsum[(cur_g << 6) + c], psum);
            psum = 0.f;
            cur_g = g;
        }
        psum += hv;
    }
    if (cur_g >= 0) atomicAdd(&hsum[(cur_g << 6) + c], psum);
}

// ---------------------------------------------------------------------------
// Layer 2: dual-node f16x2 gather + pool — lanes 0-31 = even node's channel
// pairs, lanes 32-63 = odd node's: ALL 64 lanes active, 32 rows in flight.
// Per-graph Σ agg2 @ w2_rel = (Σ agg2) @ w2_rel -> GEMM lives in finalize.
// Per-lane node sequence stays monotonic in g -> run-detection pooling valid.
// ---------------------------------------------------------------------------
__global__ __launch_bounds__(256, 4) void layer2_kernel(
        const uint* __restrict__ hb32,
        const int* __restrict__ cnt,
        const int* __restrict__ slots,
        const int* __restrict__ batch,
        float* __restrict__ esum) {
    const int wave = threadIdx.x >> 6, lane = threadIdx.x & 63;
    const int half = lane >> 5, l32 = lane & 31;
    const int base = blockIdx.x * 64;

    float psum0 = 0.f, psum1 = 0.f;
    int cur_g = -1;
    for (int i = 0; i < 8; ++i) {
        int n = base + wave * 16 + 2 * i + half;
        if (n < N_NODES) {
            int deg = cnt[n]; if (deg > CAPD) deg = CAPD;
            int dp = (deg + 15) & ~15; if (dp > CAPD) dp = CAPD;
            h2 sum = {(_Float16)0, (_Float16)0};
            const int* sl = slots + n * CAPD;
            for (int j = 0; j < dp; j += 16) {
                int4 a4 = *(const int4*)(sl + j);
                int4 b4 = *(const int4*)(sl + j + 4);
                int4 c4 = *(const int4*)(sl + j + 8);
                int4 d4 = *(const int4*)(sl + j + 12);
                uint v0 = hb32[(clampi(a4.x) << 5) + l32];
                uint v1 = hb32[(clampi(a4.y) << 5) + l32];
                uint v2 = hb32[(clampi(a4.z) << 5) + l32];
                uint v3 = hb32[(clampi(a4.w) << 5) + l32];
                uint v4 = hb32[(clampi(b4.x) << 5) + l32];
                uint v5 = hb32[(clampi(b4.y) << 5) + l32];
                uint v6 = hb32[(clampi(b4.z) << 5) + l32];
                uint v7 = hb32[(clampi(b4.w) << 5) + l32];
                uint v8 = hb32[(clampi(c4.x) << 5) + l32];
                uint v9 = hb32[(clampi(c4.y) << 5) + l32];
                uint va = hb32[(clampi(c4.z) << 5) + l32];
                uint vb = hb32[(clampi(c4.w) << 5) + l32];
                uint vc = hb32[(clampi(d4.x) << 5) + l32];
                uint vd = hb32[(clampi(d4.y) << 5) + l32];
                uint ve = hb32[(clampi(d4.z) << 5) + l32];
                uint vf = hb32[(clampi(d4.w) << 5) + l32];
                h2 t0 = (u2h(v0) + u2h(v1)) + (u2h(v2) + u2h(v3));
                h2 t1 = (u2h(v4) + u2h(v5)) + (u2h(v6) + u2h(v7));
                h2 t2 = (u2h(v8) + u2h(v9)) + (u2h(va) + u2h(vb));
                h2 t3 = (u2h(vc) + u2h(vd)) + (u2h(ve) + u2h(vf));
                sum += (t0 + t1) + (t2 + t3);
            }
            int g = batch[n];
            if (g != cur_g) {
                if (cur_g >= 0) {
                    atomicAdd(&esum[(cur_g << 6) + 2 * l32], psum0);
                    atomicAdd(&esum[(cur_g << 6) + 2 * l32 + 1], psum1);
                }
                psum0 = 0.f; psum1 = 0.f;
                cur_g = g;
            }
            psum0 += (float)sum.x;
            psum1 += (float)sum.y;
        }
    }
    if (cur_g >= 0) {
        atomicAdd(&esum[(cur_g << 6) + 2 * l32], psum0);
        atomicAdd(&esum[(cur_g << 6) + 2 * l32 + 1], psum1);
    }
}

// ---------------------------------------------------------------------------
// out[g][c] = relu( (esum[g]@w2_rel + hsum[g]@w2_root + cnt*b2) / max(cnt,1) )
// ---------------------------------------------------------------------------
__global__ void finalize_kernel(const float* __restrict__ esum,
                                const float* __restrict__ hsum,
                                const float* __restrict__ w2_rel,
                                const float* __restrict__ w2_root,
                                const float* __restrict__ b2,
                                const int* __restrict__ batch,
                                float* __restrict__ out) {
    __shared__ float s_e[HID];
    __shared__ float s_h[HID];
    const int g = blockIdx.x;
    const int c = threadIdx.x;
    s_e[c] = esum[(g << 6) + c];
    s_h[c] = hsum[(g << 6) + c];
    __syncthreads();

    int lo = 0, hi = N_NODES;
    while (lo < hi) { int m = (lo + hi) >> 1; if (batch[m] < g) lo = m + 1; else hi = m; }
    int start = lo;
    hi = N_NODES;
    while (lo < hi) { int m = (lo + hi) >> 1; if (batch[m] < g + 1) lo = m + 1; else hi = m; }
    int cntg = lo - start;

    float acc = (float)cntg * b2[c];
    #pragma unroll
    for (int k = 0; k < HID; ++k) {
        acc += s_e[k] * w2_rel[k * HID + c];
        acc += s_h[k] * w2_root[k * HID + c];
    }
    float denom = cntg > 0 ? (float)cntg : 1.f;
    out[(g << 6) + c] = fmaxf(acc / denom, 0.f);
}

// ---------------------------------------------------------------------------
extern "C" void kernel_launch(void* const* d_in, const int* in_sizes, int n_in,
                              void* d_out, int out_size, void* d_ws, size_t ws_size,
                              hipStream_t stream) {
    const float* x       = (const float*)d_in[0];
    const int*   ei      = (const int*)  d_in[1];
    const int*   batch   = (const int*)  d_in[2];
    const float* w1_rel  = (const float*)d_in[3];
    const float* b1_rel  = (const float*)d_in[4];
    const float* w1_root = (const float*)d_in[5];
    const float* w2_rel  = (const float*)d_in[6];
    const float* b2_rel  = (const float*)d_in[7];
    const float* w2_root = (const float*)d_in[8];
    float* out = (float*)d_out;

    const int* src = ei;
    const int* dst = ei + N_EDGES;

    // ws layout (bytes), peak ~40.5 MB (same as r16/r17):
    //   [0,       400000)   cnt    N int   (written by build_kernel)
    //   [400000,  465536)   hsum   256*64 f32 (zeroed)
    //   [465536,  531072)   esum   256*64 f32 (zeroed)
    //   [531072,  532636)   gcur   NB int  (zeroed)
    //   [532640, 19732640)  slots  N*48 int (unwritten tail = poison, clamped)
    //   [19732640,27732720) xb     (N+1)*40 f16  } ebuf (391*4608 uint2)
    //   [27732720,40532848) hb     (N+1)*64 f16  } aliases xb+hb; dead
    //   [19732640,34147488) ebuf (alias)           before pack_x runs
    char* wsb = (char*)d_ws;
    int*    cnt   = (int*)   (wsb);
    float*  hsum  = (float*) (wsb + 400000);
    float*  esum  = (float*) (wsb + 465536);
    int*    gcur  = (int*)   (wsb + 531072);
    int*    slots = (int*)   (wsb + 532640);
    ushort* xb    = (ushort*)(wsb + 19732640);
    ushort* hb    = (ushort*)(wsb + 27732720);
    uint2*  ebuf  = (uint2*) (wsb + 19732640);   // alias, see above

    hipMemsetAsync(wsb + 400000, 0, 132636, stream);  // hsum + esum + gcur

    scatter_kernel<<<NBLK, 256, 0, stream>>>(src, dst, gcur, ebuf);
    build_kernel<<<NB, 256, 0, stream>>>(ebuf, gcur, cnt, slots);

    {   // pack x -> f16 [N+1][40]; zero hb dummy row (after ebuf is dead)
        int total = (N_NODES + 1) * F_PAD;
        pack_x_kernel<<<(total + 255) / 256, 256, 0, stream>>>(x, xb, hb);
    }
    {   // layer 1
        int blocks = (N_NODES + 63) / 64;
        layer1_kernel<<<blocks, 256, 0, stream>>>((const uint*)xb, cnt, slots,
                                                  w1_rel, b1_rel, w1_root, batch,
                                                  hb, hsum);
    }
    {   // layer 2: gather + per-graph pooling only
        int blocks = (N_NODES + 63) / 64;
        layer2_kernel<<<blocks, 256, 0, stream>>>((const uint*)hb, cnt, slots,
                                                  batch, esum);
    }
    {   // finalize: esum@w2_rel + hsum@w2_root + bias, mean, relu
        finalize_kernel<<<N_GRAPHS, HID, 0, stream>>>(esum, hsum, w2_rel, w2_root,
                                                      b2_rel, batch, out);
    }
}